// Round 2
// baseline (2685.664 us; speedup 1.0000x reference)
//
#include <hip/hip_runtime.h>

#define TT 2048
#define BB 256
#define II 64
#define HH 128

// clang's amdgcn builtins (cvt_pkrtz, fdot2) use __fp16 2-vectors ('V2h')
typedef __fp16 h2 __attribute__((ext_vector_type(2)));

union HI { int i; h2 h; };
__device__ __forceinline__ h2  i2h(int v) { HI u; u.i = v; return u.h; }
__device__ __forceinline__ int h2i(h2 v)  { HI u; u.h = v; return u.i; }

__device__ __forceinline__ float fsig(float x) {
  // sigmoid(x) = 1/(1+e^-x); v_exp + v_rcp, err ~1e-6, graceful at +-inf
  return __builtin_amdgcn_rcpf(1.0f + __expf(-x));
}
__device__ __forceinline__ float ftanh(float x) {
  // tanh(x) = 1 - 2/(e^{2x}+1); saturates correctly for large |x|
  return 1.0f - 2.0f * __builtin_amdgcn_rcpf(1.0f + __expf(2.0f * x));
}

// One persistent block per batch row. 256 threads = 4 waves (1/SIMD).
// threads [0,128)  ("lo", j=t)    : own r_j (full dot) + n_j h-part; own h[j] state
// threads [128,256)("hi", j=t-128): own z_j (full dot) + n_j x-part
// Weights live in VGPRs as f16x2 k-pairs; h/x broadcast per step via LDS
// f16x2 pair buffer -> per-lane VGPR -> v_readlane -> SGPR -> v_dot2_f32_f16.
__global__ __launch_bounds__(256, 1) void gru_fused(
    const float* __restrict__ x,
    const float* __restrict__ Wir, const float* __restrict__ Wiz, const float* __restrict__ Win,
    const float* __restrict__ bir, const float* __restrict__ biz, const float* __restrict__ bin_,
    const float* __restrict__ Whr, const float* __restrict__ Whz, const float* __restrict__ Whn,
    const float* __restrict__ bhn, const float* __restrict__ Wc,  const float* __restrict__ bc,
    float* __restrict__ out)
{
  const int t  = threadIdx.x;
  const int b  = blockIdx.x;
  const bool lo = (t < HH);
  const int j  = lo ? t : t - HH;

  // scalar broadcast buffer: [0..63]=h f16x2 pairs, [64..95]=x f16x2 pairs (pad to 128)
  __shared__ int   sbuf[2][128];
  __shared__ float zbuf[HH];
  __shared__ float p2buf[HH];
  __shared__ float obuf[2];

  // ---- weight preload into registers (f16x2 k-pairs, column j) ----
  h2 wH[64];  // lo: Whr[:,j]   hi: Whz[:,j]
  h2 wB[64];  // lo: Whn[:,j]   hi: [0..31]=Wiz[:,j], [32..63]=Win[:,j]
  h2 wX[32];  // lo: Wir[:,j]   hi: unused
  {
    const float* WH = lo ? Whr : Whz;
    #pragma unroll
    for (int p = 0; p < 64; ++p)
      wH[p] = __builtin_amdgcn_cvt_pkrtz(WH[(2 * p) * HH + j], WH[(2 * p + 1) * HH + j]);
    if (lo) {
      #pragma unroll
      for (int p = 0; p < 64; ++p)
        wB[p] = __builtin_amdgcn_cvt_pkrtz(Whn[(2 * p) * HH + j], Whn[(2 * p + 1) * HH + j]);
      #pragma unroll
      for (int q = 0; q < 32; ++q)
        wX[q] = __builtin_amdgcn_cvt_pkrtz(Wir[(2 * q) * HH + j], Wir[(2 * q + 1) * HH + j]);
    } else {
      #pragma unroll
      for (int q = 0; q < 32; ++q) {
        wB[q]      = __builtin_amdgcn_cvt_pkrtz(Wiz[(2 * q) * HH + j], Wiz[(2 * q + 1) * HH + j]);
        wB[32 + q] = __builtin_amdgcn_cvt_pkrtz(Win[(2 * q) * HH + j], Win[(2 * q + 1) * HH + j]);
      }
      #pragma unroll
      for (int q = 0; q < 32; ++q) wX[q] = __builtin_amdgcn_cvt_pkrtz(0.0f, 0.0f);
    }
  }

  const float bias0 = lo ? bir[j] : biz[j];   // r / z bias
  const float bias1 = lo ? 0.0f   : bin_[j];  // n x-part bias (hi)
  const float bhn_j = lo ? bhn[j] : 0.0f;
  const float wc_j  = lo ? Wc[j]  : 0.0f;
  const float bc0   = bc[0];

  float hreg = 0.0f;
  float2 x2  = make_float2(0.0f, 0.0f);
  const int m = t - HH;  // hi x-pair index

  // ---- prime step-0 scalar buffer ----
  if (t < 64) sbuf[0][t] = 0;                    // h0 = 0
  if (!lo && m < 32) {
    float2 x0 = *reinterpret_cast<const float2*>(x + (size_t)b * II + 2 * m);
    sbuf[0][64 + m] = h2i(__builtin_amdgcn_cvt_pkrtz(x0.x, x0.y));
    // prefetch x for step 1
    x2 = *reinterpret_cast<const float2*>(x + ((size_t)1 * BB + b) * II + 2 * m);
  }
  __syncthreads();

  #pragma unroll 1
  for (int s = 0; s < TT; ++s) {
    const int cur = s & 1, nxt = cur ^ 1;
    const int vA = sbuf[cur][t & 63];          // lane l holds h-pair l
    const int vB = sbuf[cur][64 + (t & 31)];   // lane l holds x-pair (l&31)

    float accA, accB;
    if (lo) {
      accA = bias0;  // r preact
      accB = 0.0f;   // h . Whn[:,j]
      #pragma unroll
      for (int k = 0; k < 64; ++k) {
        h2 hk = i2h(__builtin_amdgcn_readlane(vA, k));
        accA = __builtin_amdgcn_fdot2(hk, wH[k], accA, false);
        accB = __builtin_amdgcn_fdot2(hk, wB[k], accB, false);
      }
      #pragma unroll
      for (int q = 0; q < 32; ++q) {
        h2 xq = i2h(__builtin_amdgcn_readlane(vB, q));
        accA = __builtin_amdgcn_fdot2(xq, wX[q], accA, false);
      }
    } else {
      accA = bias0;  // z preact
      accB = bias1;  // x . Win[:,j] + bin
      #pragma unroll
      for (int k = 0; k < 64; ++k) {
        h2 hk = i2h(__builtin_amdgcn_readlane(vA, k));
        accA = __builtin_amdgcn_fdot2(hk, wH[k], accA, false);
      }
      #pragma unroll
      for (int q = 0; q < 32; ++q) {
        h2 xq = i2h(__builtin_amdgcn_readlane(vB, q));
        accA = __builtin_amdgcn_fdot2(xq, wB[q], accA, false);
        accB = __builtin_amdgcn_fdot2(xq, wB[32 + q], accB, false);
      }
      zbuf[j]  = fsig(accA);
      p2buf[j] = accB;
    }
    __syncthreads();  // z / n-x-part ready

    if (lo) {
      float r = fsig(accA);
      float n = ftanh(p2buf[j] + r * (accB + bhn_j));
      float z = zbuf[j];
      hreg = (1.0f - z) * n + z * hreg;

      // per-step classifier contribution + wave reduce
      float c = hreg * wc_j;
      #pragma unroll
      for (int off = 32; off > 0; off >>= 1) c += __shfl_xor(c, off, 64);
      if ((t & 63) == 0) obuf[t >> 6] = c;

      // stage h' pairs for next step
      float hnb = __shfl_down(hreg, 1, 64);
      if (!(t & 1)) sbuf[nxt][t >> 1] = h2i(__builtin_amdgcn_cvt_pkrtz(hreg, hnb));
    } else if (m < 32) {
      // stage x_{s+1} pairs (prefetched), prefetch x_{s+2}
      sbuf[nxt][64 + m] = h2i(__builtin_amdgcn_cvt_pkrtz(x2.x, x2.y));
      const int sn = (s + 2 < TT) ? s + 2 : TT - 1;
      x2 = *reinterpret_cast<const float2*>(x + ((size_t)sn * BB + b) * II + 2 * m);
    }
    __syncthreads();  // h'/x staged, obuf ready

    if (t == 0) out[s * BB + b] = fsig(obuf[0] + obuf[1] + bc0);
  }
}

extern "C" void kernel_launch(void* const* d_in, const int* in_sizes, int n_in,
                              void* d_out, int out_size, void* d_ws, size_t ws_size,
                              hipStream_t stream) {
  const float* x    = (const float*)d_in[0];
  const float* Wir  = (const float*)d_in[1];
  const float* Wiz  = (const float*)d_in[2];
  const float* Win  = (const float*)d_in[3];
  const float* bir  = (const float*)d_in[4];
  const float* biz  = (const float*)d_in[5];
  const float* bin_ = (const float*)d_in[6];
  const float* Whr  = (const float*)d_in[7];
  const float* Whz  = (const float*)d_in[8];
  const float* Whn  = (const float*)d_in[9];
  const float* bhn  = (const float*)d_in[10];
  const float* Wc   = (const float*)d_in[11];
  const float* bc   = (const float*)d_in[12];
  float* out = (float*)d_out;

  gru_fused<<<dim3(BB), dim3(256), 0, stream>>>(
      x, Wir, Wiz, Win, bir, biz, bin_, Whr, Whz, Whn, bhn, Wc, bc, out);
}

// Round 3
// 2633.481 us; speedup vs baseline: 1.0198x; 1.0198x over previous
//
#include <hip/hip_runtime.h>

#define TT 2048
#define BB 256
#define II 64
#define HH 128

// clang's amdgcn builtins (cvt_pkrtz, fdot2) use __fp16 2-vectors ('V2h')
typedef __fp16 h2 __attribute__((ext_vector_type(2)));

union HI { int i; h2 h; };
__device__ __forceinline__ h2  i2h(int v) { HI u; u.i = v; return u.h; }
__device__ __forceinline__ int h2i(h2 v)  { HI u; u.h = v; return u.i; }

__device__ __forceinline__ float fsig(float x) {
  return __builtin_amdgcn_rcpf(1.0f + __expf(-x));
}
__device__ __forceinline__ float ftanh(float x) {
  return 1.0f - 2.0f * __builtin_amdgcn_rcpf(1.0f + __expf(2.0f * x));
}

// One persistent block per batch row. 256 threads = 4 waves (1/SIMD).
// waves 0-1 ("lo", j=t)    : r_j full dot + n_j h-part; own h[j]; epilogue
// wave  2   ("hi", m<64)   : z_j + n_j x-part dots; x staging
// wave  3   ("hi")         : z_j + n_j x-part dots; PREVIOUS step's classifier
//                            reduce (overlapped with lo epilogue)
__global__ __launch_bounds__(256, 1) void gru_fused(
    const float* __restrict__ x,
    const float* __restrict__ Wir, const float* __restrict__ Wiz, const float* __restrict__ Win,
    const float* __restrict__ bir, const float* __restrict__ biz, const float* __restrict__ bin_,
    const float* __restrict__ Whr, const float* __restrict__ Whz, const float* __restrict__ Whn,
    const float* __restrict__ bhn, const float* __restrict__ Wc,  const float* __restrict__ bc,
    float* __restrict__ out)
{
  const int t  = threadIdx.x;
  const int b  = blockIdx.x;
  const bool lo = (t < HH);
  const int j  = lo ? t : t - HH;

  // sbuf: u16[0..127] = h as f16; int[64..95] = x f16x2 pairs. Double-buffered.
  __shared__ int   sbuf[2][128];
  __shared__ float zp[2 * HH];        // interleaved {z_j, p2_j} pairs (single-buffered: RAW/WAR split by barriers)
  __shared__ float cbuf[2][HH];       // classifier contributions, double-buffered

  // ---- weight preload into registers (f16x2 k-pairs, column j) ----
  h2 wH[64];  // lo: Whr[:,j]   hi: Whz[:,j]
  h2 wB[64];  // lo: Whn[:,j]   hi: [0..31]=Wiz[:,j], [32..63]=Win[:,j]
  h2 wX[32];  // lo: Wir[:,j]   hi: unused
  {
    const float* WH = lo ? Whr : Whz;
    #pragma unroll
    for (int p = 0; p < 64; ++p)
      wH[p] = __builtin_amdgcn_cvt_pkrtz(WH[(2 * p) * HH + j], WH[(2 * p + 1) * HH + j]);
    if (lo) {
      #pragma unroll
      for (int p = 0; p < 64; ++p)
        wB[p] = __builtin_amdgcn_cvt_pkrtz(Whn[(2 * p) * HH + j], Whn[(2 * p + 1) * HH + j]);
      #pragma unroll
      for (int q = 0; q < 32; ++q)
        wX[q] = __builtin_amdgcn_cvt_pkrtz(Wir[(2 * q) * HH + j], Wir[(2 * q + 1) * HH + j]);
    } else {
      #pragma unroll
      for (int q = 0; q < 32; ++q) {
        wB[q]      = __builtin_amdgcn_cvt_pkrtz(Wiz[(2 * q) * HH + j], Wiz[(2 * q + 1) * HH + j]);
        wB[32 + q] = __builtin_amdgcn_cvt_pkrtz(Win[(2 * q) * HH + j], Win[(2 * q + 1) * HH + j]);
      }
      #pragma unroll
      for (int q = 0; q < 32; ++q) wX[q] = __builtin_amdgcn_cvt_pkrtz(0.0f, 0.0f);
    }
  }

  const float bias0 = lo ? bir[j] : biz[j];   // r / z bias
  const float bias1 = lo ? 0.0f   : bin_[j];  // n x-part bias (hi)
  const float bhn_j = lo ? bhn[j] : 0.0f;
  const float wc_j  = lo ? Wc[j]  : 0.0f;
  const float bc0   = bc[0];

  float hreg = 0.0f;
  float2 x2  = make_float2(0.0f, 0.0f);
  const int m = t - HH;              // hi lane index within [0,128)
  const bool w3 = (t >= 192);        // wave 3: classifier reducer
  const int cl = t - 192;            // wave-3 lane

  // ---- prime step-0 buffers ----
  if (t < 64) sbuf[0][t] = 0;        // h0 = 0 (f16 pairs)
  if (!lo && m < 32) {
    float2 x0 = *reinterpret_cast<const float2*>(x + (size_t)b * II + 2 * m);
    sbuf[0][64 + m] = h2i(__builtin_amdgcn_cvt_pkrtz(x0.x, x0.y));
    x2 = *reinterpret_cast<const float2*>(x + ((size_t)1 * BB + b) * II + 2 * m);
  }
  __syncthreads();

  #pragma unroll 1
  for (int s = 0; s < TT; ++s) {
    const int cur = s & 1, nxt = cur ^ 1;
    const int vA = sbuf[cur][t & 63];          // h f16x2 pair (t&63)
    const int vB = sbuf[cur][64 + (t & 31)];   // x f16x2 pair (t&31)

    float2 cp = make_float2(0.0f, 0.0f);
    if (w3 && s > 0) cp = *reinterpret_cast<const float2*>(&cbuf[nxt][2 * cl]);

    float accA, accB, rr = 0.0f;
    if (lo) {
      accA = bias0;  // r preact
      accB = 0.0f;   // h . Whn[:,j]
      #pragma unroll
      for (int k = 0; k < 64; ++k) {
        h2 hk = i2h(__builtin_amdgcn_readlane(vA, k));
        accA = __builtin_amdgcn_fdot2(hk, wH[k], accA, false);
        accB = __builtin_amdgcn_fdot2(hk, wB[k], accB, false);
      }
      #pragma unroll
      for (int q = 0; q < 32; ++q) {
        h2 xq = i2h(__builtin_amdgcn_readlane(vB, q));
        accA = __builtin_amdgcn_fdot2(xq, wX[q], accA, false);
      }
      rr = fsig(accA);   // r ready pre-barrier (independent of hi)
    } else {
      accA = bias0;  // z preact
      accB = bias1;  // x . Win[:,j] + bin
      #pragma unroll
      for (int k = 0; k < 64; ++k) {
        h2 hk = i2h(__builtin_amdgcn_readlane(vA, k));
        accA = __builtin_amdgcn_fdot2(hk, wH[k], accA, false);
      }
      #pragma unroll
      for (int q = 0; q < 32; ++q) {
        h2 xq = i2h(__builtin_amdgcn_readlane(vB, q));
        accA = __builtin_amdgcn_fdot2(xq, wB[q], accA, false);
        accB = __builtin_amdgcn_fdot2(xq, wB[32 + q], accB, false);
      }
      *reinterpret_cast<float2*>(&zp[2 * j]) = make_float2(fsig(accA), accB);
    }
    __syncthreads();  // zp ready

    if (lo) {
      float2 z_p2 = *reinterpret_cast<const float2*>(&zp[2 * j]);
      float n = ftanh(z_p2.y + rr * (accB + bhn_j));
      float z = z_p2.x;
      hreg = (1.0f - z) * n + z * hreg;
      ((__fp16*)&sbuf[nxt][0])[j] = (__fp16)hreg;   // ds_write_b16, 2-way = free
      cbuf[cur][j] = hreg * wc_j;
    } else if (!w3) {
      if (m < 32) {
        sbuf[nxt][64 + m] = h2i(__builtin_amdgcn_cvt_pkrtz(x2.x, x2.y));
        const int sn = (s + 2 < TT) ? s + 2 : TT - 1;
        x2 = *reinterpret_cast<const float2*>(x + ((size_t)sn * BB + b) * II + 2 * m);
      }
    } else if (s > 0) {
      // reduce previous step's classifier contributions (overlaps lo epilogue)
      float c = cp.x + cp.y;
      #pragma unroll
      for (int off = 32; off > 0; off >>= 1) c += __shfl_xor(c, off, 64);
      if (cl == 0) out[(s - 1) * BB + b] = fsig(c + bc0);
    }
    __syncthreads();  // h'/x/cbuf staged
  }

  // tail: classifier for the last step
  if (w3) {
    float2 cp = *reinterpret_cast<const float2*>(&cbuf[(TT - 1) & 1][2 * cl]);
    float c = cp.x + cp.y;
    #pragma unroll
    for (int off = 32; off > 0; off >>= 1) c += __shfl_xor(c, off, 64);
    if (cl == 0) out[(TT - 1) * BB + b] = fsig(c + bc0);
  }
}

extern "C" void kernel_launch(void* const* d_in, const int* in_sizes, int n_in,
                              void* d_out, int out_size, void* d_ws, size_t ws_size,
                              hipStream_t stream) {
  const float* x    = (const float*)d_in[0];
  const float* Wir  = (const float*)d_in[1];
  const float* Wiz  = (const float*)d_in[2];
  const float* Win  = (const float*)d_in[3];
  const float* bir  = (const float*)d_in[4];
  const float* biz  = (const float*)d_in[5];
  const float* bin_ = (const float*)d_in[6];
  const float* Whr  = (const float*)d_in[7];
  const float* Whz  = (const float*)d_in[8];
  const float* Whn  = (const float*)d_in[9];
  const float* bhn  = (const float*)d_in[10];
  const float* Wc   = (const float*)d_in[11];
  const float* bc   = (const float*)d_in[12];
  float* out = (float*)d_out;

  gru_fused<<<dim3(BB), dim3(256), 0, stream>>>(
      x, Wir, Wiz, Win, bir, biz, bin_, Whr, Whz, Whn, bhn, Wc, bc, out);
}

// Round 4
// 2000.505 us; speedup vs baseline: 1.3425x; 1.3164x over previous
//
#include <hip/hip_runtime.h>

#define TT 2048
#define BB 256
#define II 64
#define HH 128

typedef __fp16 f16;
typedef __fp16 h2  __attribute__((ext_vector_type(2)));
typedef __fp16 v8h __attribute__((ext_vector_type(8)));
typedef float  v4f __attribute__((ext_vector_type(4)));

union HI { int i; h2 h; };
__device__ __forceinline__ h2  i2h(int v) { HI u; u.i = v; return u.h; }
__device__ __forceinline__ int h2i(h2 v)  { HI u; u.h = v; return u.i; }

__device__ __forceinline__ float fsig(float x) {
  return __builtin_amdgcn_rcpf(1.0f + __expf(-x));
}
__device__ __forceinline__ float ftanh(float x) {
  return 1.0f - 2.0f * __builtin_amdgcn_rcpf(1.0f + __expf(2.0f * x));
}

// One block per batch row, 256 threads = 4 waves (1/SIMD).
// A-operand: M=16 tile, only row 0 real = [h(128) | x(64)] f16 in LDS.
// Wave w owns output cols [32w, 32w+32) for all gates; B-frags register-resident.
// 36 mfma_f32_16x16x32_f16 per step; epilogue on quad-0 lanes (C row 0).
// Classifier for step s-1 computed at step s from LDS h by wave 2 / quad 1.
__global__ __launch_bounds__(256, 1) void gru_mfma(
    const float* __restrict__ x,
    const float* __restrict__ Wir, const float* __restrict__ Wiz, const float* __restrict__ Win,
    const float* __restrict__ bir, const float* __restrict__ biz, const float* __restrict__ bin_,
    const float* __restrict__ Whr, const float* __restrict__ Whz, const float* __restrict__ Whn,
    const float* __restrict__ bhn, const float* __restrict__ Wc,  const float* __restrict__ bc,
    float* __restrict__ out)
{
  const int t = threadIdx.x, b = blockIdx.x;
  const int w = t >> 6;     // wave id
  const int l = t & 63;     // lane
  const int q = l >> 4;     // quad
  const int r = l & 15;

  // row stride 200 f16 = 400 B (16B-aligned, uniform 8-access/bank for b128)
  __shared__ f16 buf[2][16][200];

  // zero LDS (rows 1..15 must be zero forever; h0 = 0)
  for (int i = t; i < 2 * 16 * 200; i += 256) ((f16*)buf)[i] = (f16)0.f;

  // ---- resident B fragments: B[k=32kt+8q+j][n=32w+16ct+r] ----
  v8h br_[6][2], bz_[6][2], bnh_[4][2], bnx_[2][2];
  for (int kt = 0; kt < 6; ++kt)
    for (int ct = 0; ct < 2; ++ct) {
      const int n = 32 * w + 16 * ct + r;
      v8h vr, vz;
      for (int j = 0; j < 8; ++j) {
        const int kg = 32 * kt + 8 * q + j;
        vr[j] = (f16)((kg < HH) ? Whr[kg * HH + n] : Wir[(kg - HH) * HH + n]);
        vz[j] = (f16)((kg < HH) ? Whz[kg * HH + n] : Wiz[(kg - HH) * HH + n]);
      }
      br_[kt][ct] = vr; bz_[kt][ct] = vz;
    }
  for (int kt = 0; kt < 4; ++kt)
    for (int ct = 0; ct < 2; ++ct) {
      const int n = 32 * w + 16 * ct + r;
      v8h v;
      for (int j = 0; j < 8; ++j) v[j] = (f16)Whn[(32 * kt + 8 * q + j) * HH + n];
      bnh_[kt][ct] = v;
    }
  for (int kt = 0; kt < 2; ++kt)
    for (int ct = 0; ct < 2; ++ct) {
      const int n = 32 * w + 16 * ct + r;
      v8h v;
      for (int j = 0; j < 8; ++j) v[j] = (f16)Win[(32 * kt + 8 * q + j) * HH + n];
      bnx_[kt][ct] = v;
    }

  float birc[2], bizc[2], binc[2], bhnc[2], hst[2] = {0.f, 0.f};
  for (int ct = 0; ct < 2; ++ct) {
    const int n = 32 * w + 16 * ct + r;
    birc[ct] = bir[n]; bizc[ct] = biz[n]; binc[ct] = bin_[n]; bhnc[ct] = bhn[n];
  }
  const float bc0 = bc[0];

  h2 wcp[4];
  if (w == 2 && q == 1) {
    for (int p = 0; p < 4; ++p)
      wcp[p] = __builtin_amdgcn_cvt_pkrtz(Wc[8 * r + 2 * p], Wc[8 * r + 2 * p + 1]);
  }

  __syncthreads();  // zero-fill visible

  // stage x[0] into buf[0] row 0 cols [128,192)
  float4 xa = make_float4(0, 0, 0, 0), xb = make_float4(0, 0, 0, 0);
  if (t < 16) {
    float4 x0 = *(const float4*)(x + (size_t)b * II + 4 * t);
    int2 p;
    p.x = h2i(__builtin_amdgcn_cvt_pkrtz(x0.x, x0.y));
    p.y = h2i(__builtin_amdgcn_cvt_pkrtz(x0.z, x0.w));
    *(int2*)&buf[0][0][128 + 4 * t] = p;
  }
  if (w == 0 && q == 1) {  // 2-deep x prefetch
    xa = *(const float4*)(x + ((size_t)1 * BB + b) * II + 4 * r);
    xb = *(const float4*)(x + ((size_t)2 * BB + b) * II + 4 * r);
  }
  __syncthreads();

  #pragma unroll 1
  for (int s = 0; s < TT; ++s) {
    const int cur = s & 1, nxt = cur ^ 1;

    // classifier for step s-1: h_{s} is in buf[cur] row 0 (wave 2, quad 1)
    if (w == 2 && q == 1 && s > 0) {
      const int4 hv = *(const int4*)&buf[cur][0][8 * r];
      float c = 0.f;
      c = __builtin_amdgcn_fdot2(i2h(hv.x), wcp[0], c, false);
      c = __builtin_amdgcn_fdot2(i2h(hv.y), wcp[1], c, false);
      c = __builtin_amdgcn_fdot2(i2h(hv.z), wcp[2], c, false);
      c = __builtin_amdgcn_fdot2(i2h(hv.w), wcp[3], c, false);
      c += __shfl_xor(c, 1, 64);
      c += __shfl_xor(c, 2, 64);
      c += __shfl_xor(c, 4, 64);
      c += __shfl_xor(c, 8, 64);
      if (r == 0) out[(size_t)(s - 1) * BB + b] = fsig(c + bc0);
    }

    // A-fragments: A[m=r][k=32kt+8q+j]
    v8h af[6];
    #pragma unroll
    for (int kt = 0; kt < 6; ++kt)
      af[kt] = *(const v8h*)&buf[cur][r][32 * kt + 8 * q];

    v4f ar[2], az[2], anh[2], anx[2];
    #pragma unroll
    for (int ct = 0; ct < 2; ++ct) {
      v4f a = {0.f, 0.f, 0.f, 0.f};
      #pragma unroll
      for (int kt = 0; kt < 6; ++kt)
        a = __builtin_amdgcn_mfma_f32_16x16x32_f16(af[kt], br_[kt][ct], a, 0, 0, 0);
      ar[ct] = a;
      a = (v4f){0.f, 0.f, 0.f, 0.f};
      #pragma unroll
      for (int kt = 0; kt < 6; ++kt)
        a = __builtin_amdgcn_mfma_f32_16x16x32_f16(af[kt], bz_[kt][ct], a, 0, 0, 0);
      az[ct] = a;
      a = (v4f){0.f, 0.f, 0.f, 0.f};
      #pragma unroll
      for (int kt = 0; kt < 4; ++kt)
        a = __builtin_amdgcn_mfma_f32_16x16x32_f16(af[kt], bnh_[kt][ct], a, 0, 0, 0);
      anh[ct] = a;
      a = (v4f){0.f, 0.f, 0.f, 0.f};
      #pragma unroll
      for (int kt = 0; kt < 2; ++kt)
        a = __builtin_amdgcn_mfma_f32_16x16x32_f16(af[4 + kt], bnx_[kt][ct], a, 0, 0, 0);
      anx[ct] = a;
    }

    // epilogue: C row 0 lives in reg 0 of quad-0 lanes; col = 32w+16ct+r
    if (q == 0) {
      #pragma unroll
      for (int ct = 0; ct < 2; ++ct) {
        float rr = fsig(ar[ct][0] + birc[ct]);
        float zz = fsig(az[ct][0] + bizc[ct]);
        float nn = ftanh(anx[ct][0] + binc[ct] + rr * (anh[ct][0] + bhnc[ct]));
        hst[ct] = (1.f - zz) * nn + zz * hst[ct];
        buf[nxt][0][32 * w + 16 * ct + r] = (f16)hst[ct];
      }
    }
    // stage x_{s+1} (held in xa), prefetch x_{s+3}
    if (w == 0 && q == 1) {
      int2 p;
      p.x = h2i(__builtin_amdgcn_cvt_pkrtz(xa.x, xa.y));
      p.y = h2i(__builtin_amdgcn_cvt_pkrtz(xa.z, xa.w));
      *(int2*)&buf[nxt][0][128 + 4 * r] = p;
      xa = xb;
      const int sn = (s + 3 < TT) ? s + 3 : TT - 1;
      xb = *(const float4*)(x + ((size_t)sn * BB + b) * II + 4 * r);
    }
    __syncthreads();
  }

  // tail: out[TT-1] from h_final in buf[0] (nxt of last iter)
  if (w == 2 && q == 1) {
    const int4 hv = *(const int4*)&buf[0][0][8 * r];
    float c = 0.f;
    c = __builtin_amdgcn_fdot2(i2h(hv.x), wcp[0], c, false);
    c = __builtin_amdgcn_fdot2(i2h(hv.y), wcp[1], c, false);
    c = __builtin_amdgcn_fdot2(i2h(hv.z), wcp[2], c, false);
    c = __builtin_amdgcn_fdot2(i2h(hv.w), wcp[3], c, false);
    c += __shfl_xor(c, 1, 64);
    c += __shfl_xor(c, 2, 64);
    c += __shfl_xor(c, 4, 64);
    c += __shfl_xor(c, 8, 64);
    if (r == 0) out[(size_t)(TT - 1) * BB + b] = fsig(c + bc0);
  }
}

extern "C" void kernel_launch(void* const* d_in, const int* in_sizes, int n_in,
                              void* d_out, int out_size, void* d_ws, size_t ws_size,
                              hipStream_t stream) {
  const float* x    = (const float*)d_in[0];
  const float* Wir  = (const float*)d_in[1];
  const float* Wiz  = (const float*)d_in[2];
  const float* Win  = (const float*)d_in[3];
  const float* bir  = (const float*)d_in[4];
  const float* biz  = (const float*)d_in[5];
  const float* bin_ = (const float*)d_in[6];
  const float* Whr  = (const float*)d_in[7];
  const float* Whz  = (const float*)d_in[8];
  const float* Whn  = (const float*)d_in[9];
  const float* bhn  = (const float*)d_in[10];
  const float* Wc   = (const float*)d_in[11];
  const float* bc   = (const float*)d_in[12];
  float* out = (float*)d_out;

  gru_mfma<<<dim3(BB), dim3(256), 0, stream>>>(
      x, Wir, Wiz, Win, bir, biz, bin_, Whr, Whz, Whn, bhn, Wc, bc, out);
}